// Round 1
// baseline (306.896 us; speedup 1.0000x reference)
//
#include <hip/hip_runtime.h>
#include <hip/hip_bf16.h>

typedef __attribute__((ext_vector_type(8))) __bf16 bf16x8;
typedef __attribute__((ext_vector_type(4))) float f32x4;

#define DIM 1024
#define SLEN 2048
#define NH 16
#define HD 64

__device__ __forceinline__ f32x4 MFMA(bf16x8 a, bf16x8 b, f32x4 c) {
    return __builtin_amdgcn_mfma_f32_16x16x32_bf16(a, b, c, 0, 0, 0);
}

// ---------------- f32 -> bf16 convert (n % 8 == 0) ----------------
__global__ __launch_bounds__(256) void cvt_bf16(const float* __restrict__ in,
                                                __bf16* __restrict__ out, int n) {
    int i = (blockIdx.x * blockDim.x + threadIdx.x) * 8;
    if (i >= n) return;
    f32x4 a = *reinterpret_cast<const f32x4*>(in + i);
    f32x4 b = *reinterpret_cast<const f32x4*>(in + i + 4);
    bf16x8 o;
#pragma unroll
    for (int j = 0; j < 4; ++j) { o[j] = (__bf16)a[j]; o[j + 4] = (__bf16)b[j]; }
    *reinterpret_cast<bf16x8*>(out + i) = o;
}

// ---------------- RoPE in-place on bf16 [nrows][DIM] ----------------
__global__ __launch_bounds__(256) void rope_kernel(__bf16* __restrict__ t, int nrows) {
    int idx = blockIdx.x * blockDim.x + threadIdx.x;
    if (idx >= nrows * (DIM / 2)) return;
    int row = idx >> 9;              // / 512 pairs per row
    int p = idx & 511;
    int head = p >> 5;               // 32 pairs per head
    int j = p & 31;
    int s = row & (SLEN - 1);
    // inv_freq = 10000^(-j/32)
    float inv = expf(-0.28782313662425574f * (float)j);
    float angle = (float)s * inv;
    float sn, cs;
    sincosf(angle, &sn, &cs);
    size_t base = (size_t)row * DIM + head * HD + 2 * j;
    float e = (float)t[base], o = (float)t[base + 1];
    t[base] = (__bf16)(e * cs - o * sn);
    t[base + 1] = (__bf16)(e * sn + o * cs);
}

// ---------------- GEMM: C[M][N] = A[M][K] * B[N][K]^T (bf16 in, OutT out) --------
// 64x64 tile, BK=64, 4 waves in 2x2, each wave 32x32 via 2x2 mfma 16x16x32
template <typename OutT>
__global__ __launch_bounds__(256) void gemm_bt(const __bf16* __restrict__ A,
                                               const __bf16* __restrict__ B,
                                               OutT* __restrict__ C,
                                               int M, int N, int K) {
    __shared__ alignas(16) __bf16 Alds[64][72];
    __shared__ alignas(16) __bf16 Blds[64][72];
    const int tid = threadIdx.x;
    const int lane = tid & 63;
    const int w = tid >> 6;
    const int wr = w >> 1, wc = w & 1;
    const int l15 = lane & 15, lhi = lane >> 4;
    const int m0 = blockIdx.y * 64;
    const int n0 = blockIdx.x * 64;

    f32x4 acc[2][2] = {};

    for (int kt = 0; kt < K; kt += 64) {
#pragma unroll
        for (int i = 0; i < 2; ++i) {
            int slot = tid + i * 256;
            int row = slot >> 3;
            int cb = (slot & 7) * 8;
            *reinterpret_cast<bf16x8*>(&Alds[row][cb]) =
                *reinterpret_cast<const bf16x8*>(&A[(size_t)(m0 + row) * K + kt + cb]);
            *reinterpret_cast<bf16x8*>(&Blds[row][cb]) =
                *reinterpret_cast<const bf16x8*>(&B[(size_t)(n0 + row) * K + kt + cb]);
        }
        __syncthreads();
#pragma unroll
        for (int kk = 0; kk < 2; ++kk) {
            bf16x8 a0 = *reinterpret_cast<const bf16x8*>(&Alds[wr * 32 + l15][kk * 32 + lhi * 8]);
            bf16x8 a1 = *reinterpret_cast<const bf16x8*>(&Alds[wr * 32 + 16 + l15][kk * 32 + lhi * 8]);
            bf16x8 b0 = *reinterpret_cast<const bf16x8*>(&Blds[wc * 32 + l15][kk * 32 + lhi * 8]);
            bf16x8 b1 = *reinterpret_cast<const bf16x8*>(&Blds[wc * 32 + 16 + l15][kk * 32 + lhi * 8]);
            acc[0][0] = MFMA(a0, b0, acc[0][0]);
            acc[0][1] = MFMA(a0, b1, acc[0][1]);
            acc[1][0] = MFMA(a1, b0, acc[1][0]);
            acc[1][1] = MFMA(a1, b1, acc[1][1]);
        }
        __syncthreads();
    }
#pragma unroll
    for (int mb = 0; mb < 2; ++mb)
#pragma unroll
        for (int nb = 0; nb < 2; ++nb)
#pragma unroll
            for (int r = 0; r < 4; ++r) {
                int row = m0 + wr * 32 + mb * 16 + lhi * 4 + r;
                int col = n0 + wc * 32 + nb * 16 + l15;
                C[(size_t)row * N + col] = (OutT)acc[mb][nb][r];
            }
}

// ---------------- causal flash attention ----------------
// grid (32 q-tiles, 2 batch, 16 heads), block 256 (4 waves x 16 q-rows)
__global__ __launch_bounds__(256) void attn_kernel(const __bf16* __restrict__ Q,
                                                   const __bf16* __restrict__ K,
                                                   const __bf16* __restrict__ V,
                                                   __bf16* __restrict__ Y) {
    __shared__ alignas(16) __bf16 Klds[64][72];
    __shared__ alignas(16) __bf16 Vt[64][72];
    __shared__ alignas(16) __bf16 Plds[4][16][72];

    const int tid = threadIdx.x;
    const int lane = tid & 63;
    const int w = tid >> 6;
    const int l15 = lane & 15, lhi = lane >> 4;
    const int qt = blockIdx.x;
    const int b = blockIdx.y;
    const int h = blockIdx.z;
    const int q0 = qt * 64;

    const size_t qrow = (size_t)(b * SLEN + q0 + w * 16 + l15) * DIM + h * HD;
    bf16x8 qf0 = *reinterpret_cast<const bf16x8*>(&Q[qrow + lhi * 8]);
    bf16x8 qf1 = *reinterpret_cast<const bf16x8*>(&Q[qrow + 32 + lhi * 8]);

    float m[4], lsum[4];
    f32x4 accO[4] = {};
#pragma unroll
    for (int r = 0; r < 4; ++r) { m[r] = -1e30f; lsum[r] = 0.f; }

    const int ntile = qt + 1;
    for (int kt = 0; kt < ntile; ++kt) {
        // stage K row-major, V transposed
#pragma unroll
        for (int i = 0; i < 2; ++i) {
            int slot = tid + i * 256;
            int row = slot >> 3;
            int cb = (slot & 7) * 8;
            size_t g = (size_t)(b * SLEN + kt * 64 + row) * DIM + h * HD + cb;
            *reinterpret_cast<bf16x8*>(&Klds[row][cb]) =
                *reinterpret_cast<const bf16x8*>(&K[g]);
            bf16x8 vv = *reinterpret_cast<const bf16x8*>(&V[g]);
#pragma unroll
            for (int jj = 0; jj < 8; ++jj) Vt[cb + jj][row] = vv[jj];
        }
        __syncthreads();

        // S = Q K^T  (16 q-rows x 64 keys per wave)
        f32x4 sf[4];
#pragma unroll
        for (int nb = 0; nb < 4; ++nb) {
            f32x4 a = {0.f, 0.f, 0.f, 0.f};
            bf16x8 k0 = *reinterpret_cast<const bf16x8*>(&Klds[nb * 16 + l15][lhi * 8]);
            bf16x8 k1 = *reinterpret_cast<const bf16x8*>(&Klds[nb * 16 + l15][32 + lhi * 8]);
            a = MFMA(qf0, k0, a);
            a = MFMA(qf1, k1, a);
            sf[nb] = a;
        }

        const int keyb = kt * 64;
#pragma unroll
        for (int r = 0; r < 4; ++r) {
            const int qg = q0 + w * 16 + lhi * 4 + r;
            float mx = -1e30f;
#pragma unroll
            for (int nb = 0; nb < 4; ++nb) {
                int key = keyb + nb * 16 + l15;
                float v = sf[nb][r] * 0.125f;
                v = (key <= qg) ? v : -1e30f;
                sf[nb][r] = v;
                mx = fmaxf(mx, v);
            }
#pragma unroll
            for (int off = 1; off < 16; off <<= 1)
                mx = fmaxf(mx, __shfl_xor(mx, off));
            float mn = fmaxf(m[r], mx);
            float corr = __expf(m[r] - mn);
            m[r] = mn;
            float rs = 0.f;
#pragma unroll
            for (int nb = 0; nb < 4; ++nb) {
                float p = __expf(sf[nb][r] - mn);
                rs += p;
                Plds[w][lhi * 4 + r][nb * 16 + l15] = (__bf16)p;
            }
#pragma unroll
            for (int off = 1; off < 16; off <<= 1)
                rs += __shfl_xor(rs, off);
            lsum[r] = lsum[r] * corr + rs;
#pragma unroll
            for (int n = 0; n < 4; ++n) accO[n][r] *= corr;
        }

        // O += P V
#pragma unroll
        for (int nd = 0; nd < 4; ++nd) {
#pragma unroll
            for (int kk = 0; kk < 2; ++kk) {
                bf16x8 pf = *reinterpret_cast<const bf16x8*>(&Plds[w][l15][kk * 32 + lhi * 8]);
                bf16x8 vf = *reinterpret_cast<const bf16x8*>(&Vt[nd * 16 + l15][kk * 32 + lhi * 8]);
                accO[nd] = MFMA(pf, vf, accO[nd]);
            }
        }
        __syncthreads();
    }

    // epilogue: O / l
#pragma unroll
    for (int nd = 0; nd < 4; ++nd)
#pragma unroll
        for (int r = 0; r < 4; ++r) {
            size_t orow = (size_t)(b * SLEN + q0 + w * 16 + lhi * 4 + r) * DIM + h * HD + nd * 16 + l15;
            Y[orow] = (__bf16)(accO[nd][r] / lsum[r]);
        }
}

// ---------------- launcher ----------------
extern "C" void kernel_launch(void* const* d_in, const int* in_sizes, int n_in,
                              void* d_out, int out_size, void* d_ws, size_t ws_size,
                              hipStream_t stream) {
    const float* x = (const float*)d_in[0];
    const float* Wq = (const float*)d_in[1];
    const float* Wk = (const float*)d_in[2];
    const float* Wv = (const float*)d_in[3];
    const float* Wo = (const float*)d_in[4];
    float* out = (float*)d_out;

    const size_t XN = (size_t)4096 * 1024;  // x/q/k/v/y elements
    const size_t WN = (size_t)1024 * 1024;

    __bf16* xb = (__bf16*)d_ws;       // also reused as yb after last read of xb
    __bf16* qb = xb + XN;
    __bf16* kb = qb + XN;
    __bf16* vb = kb + XN;
    __bf16* wqb = vb + XN;
    __bf16* wkb = wqb + WN;
    __bf16* wvb = wkb + WN;
    __bf16* wob = wvb + WN;
    __bf16* yb = xb;  // alias: attn writes y after x's last read (V GEMM)

    cvt_bf16<<<XN / 8 / 256, 256, 0, stream>>>(x, xb, (int)XN);
    cvt_bf16<<<WN / 8 / 256, 256, 0, stream>>>(Wq, wqb, (int)WN);
    cvt_bf16<<<WN / 8 / 256, 256, 0, stream>>>(Wk, wkb, (int)WN);
    cvt_bf16<<<WN / 8 / 256, 256, 0, stream>>>(Wv, wvb, (int)WN);
    cvt_bf16<<<WN / 8 / 256, 256, 0, stream>>>(Wo, wob, (int)WN);

    dim3 gg(1024 / 64, 4096 / 64);
    gemm_bt<__bf16><<<gg, 256, 0, stream>>>(xb, wqb, qb, 4096, 1024, 1024);
    gemm_bt<__bf16><<<gg, 256, 0, stream>>>(xb, wkb, kb, 4096, 1024, 1024);
    gemm_bt<__bf16><<<gg, 256, 0, stream>>>(xb, wvb, vb, 4096, 1024, 1024);

    int pairs = 4096 * (DIM / 2);
    rope_kernel<<<(pairs + 255) / 256, 256, 0, stream>>>(qb, 4096);
    rope_kernel<<<(pairs + 255) / 256, 256, 0, stream>>>(kb, 4096);

    dim3 ga(32, 2, 16);
    attn_kernel<<<ga, 256, 0, stream>>>(qb, kb, vb, yb);

    gemm_bt<float><<<gg, 256, 0, stream>>>(yb, wob, out, 4096, 1024, 1024);
}

// Round 2
// 173.287 us; speedup vs baseline: 1.7710x; 1.7710x over previous
//
#include <hip/hip_runtime.h>
#include <hip/hip_bf16.h>

typedef __attribute__((ext_vector_type(8))) __bf16 bf16x8;
typedef __attribute__((ext_vector_type(4))) __bf16 bf16x4;
typedef __attribute__((ext_vector_type(4))) float f32x4;

#define DIM 1024
#define SLEN 2048
#define NH 16
#define HD 64

__device__ __forceinline__ f32x4 MFMA(bf16x8 a, bf16x8 b, f32x4 c) {
    return __builtin_amdgcn_mfma_f32_16x16x32_bf16(a, b, c, 0, 0, 0);
}

// ---------------- f32 -> bf16 convert (n % 8 == 0) ----------------
__global__ __launch_bounds__(256) void cvt_bf16(const float* __restrict__ in,
                                                __bf16* __restrict__ out, int n) {
    int i = (blockIdx.x * blockDim.x + threadIdx.x) * 8;
    if (i >= n) return;
    f32x4 a = *reinterpret_cast<const f32x4*>(in + i);
    f32x4 b = *reinterpret_cast<const f32x4*>(in + i + 4);
    bf16x8 o;
#pragma unroll
    for (int j = 0; j < 4; ++j) { o[j] = (__bf16)a[j]; o[j + 4] = (__bf16)b[j]; }
    *reinterpret_cast<bf16x8*>(out + i) = o;
}

// ---------------- RoPE in-place on bf16 [nrows][DIM], with output scale --------
__global__ __launch_bounds__(256) void rope_kernel(__bf16* __restrict__ t, int nrows,
                                                   float scale) {
    int idx = blockIdx.x * blockDim.x + threadIdx.x;
    if (idx >= nrows * (DIM / 2)) return;
    int row = idx >> 9;
    int p = idx & 511;
    int head = p >> 5;
    int j = p & 31;
    int s = row & (SLEN - 1);
    float inv = expf(-0.28782313662425574f * (float)j);
    float angle = (float)s * inv;
    float sn, cs;
    sincosf(angle, &sn, &cs);
    size_t base = (size_t)row * DIM + head * HD + 2 * j;
    float e = (float)t[base], o = (float)t[base + 1];
    t[base] = (__bf16)((e * cs - o * sn) * scale);
    t[base + 1] = (__bf16)((e * sn + o * cs) * scale);
}

// ---------------- fused QKV GEMM: 128x128 tile, BK=64, global_load_lds --------
// C_s[M][1024] = X[M][K] * Ws[1024][K]^T for s in {q,k,v}; grid.x selects segment
__global__ __launch_bounds__(256) void gemm_qkv(const __bf16* __restrict__ X,
                                                const __bf16* __restrict__ Wq,
                                                const __bf16* __restrict__ Wk,
                                                const __bf16* __restrict__ Wv,
                                                __bf16* __restrict__ Qo,
                                                __bf16* __restrict__ Ko,
                                                __bf16* __restrict__ Vo) {
    __shared__ alignas(16) __bf16 Alds[128 * 64];
    __shared__ alignas(16) __bf16 Blds[128 * 64];
    const int tid = threadIdx.x;
    const int lane = tid & 63;
    const int w = tid >> 6;
    const int wr = w >> 1, wc = w & 1;
    const int l15 = lane & 15, lhi = lane >> 4;
    const int m0 = blockIdx.y * 128;
    const int n0g = blockIdx.x * 128;
    const int seg = n0g >> 10;
    const int n0 = n0g & 1023;
    const __bf16* __restrict__ B = seg == 0 ? Wq : seg == 1 ? Wk : Wv;
    __bf16* __restrict__ O = seg == 0 ? Qo : seg == 1 ? Ko : Vo;
    const int K = 1024, N = 1024;

    const int lrow = lane >> 3;       // 0..7
    const int lcol = (lane & 7) * 8;  // 0..56

    f32x4 acc[4][4] = {};

    for (int kt = 0; kt < K; kt += 64) {
#pragma unroll
        for (int c = 0; c < 4; ++c) {
            int r0 = c * 32 + w * 8;
            const __bf16* sa = &X[(size_t)(m0 + r0 + lrow) * K + kt + lcol];
            const __bf16* sb = &B[(size_t)(n0 + r0 + lrow) * K + kt + lcol];
            __builtin_amdgcn_global_load_lds((const __attribute__((address_space(1))) void*)sa,
                                             (__attribute__((address_space(3))) void*)&Alds[r0 * 64],
                                             16, 0, 0);
            __builtin_amdgcn_global_load_lds((const __attribute__((address_space(1))) void*)sb,
                                             (__attribute__((address_space(3))) void*)&Blds[r0 * 64],
                                             16, 0, 0);
        }
        __syncthreads();
#pragma unroll
        for (int kk = 0; kk < 2; ++kk) {
            bf16x8 af[4], bfr[4];
#pragma unroll
            for (int i = 0; i < 4; ++i) {
                af[i] = *(const bf16x8*)&Alds[(wr * 64 + i * 16 + l15) * 64 + kk * 32 + lhi * 8];
                bfr[i] = *(const bf16x8*)&Blds[(wc * 64 + i * 16 + l15) * 64 + kk * 32 + lhi * 8];
            }
#pragma unroll
            for (int i = 0; i < 4; ++i)
#pragma unroll
                for (int j = 0; j < 4; ++j)
                    acc[i][j] = MFMA(af[i], bfr[j], acc[i][j]);
        }
        __syncthreads();
    }
#pragma unroll
    for (int i = 0; i < 4; ++i)
#pragma unroll
        for (int j = 0; j < 4; ++j)
#pragma unroll
            for (int r = 0; r < 4; ++r) {
                int row = m0 + wr * 64 + i * 16 + lhi * 4 + r;
                int col = n0 + wc * 64 + j * 16 + l15;
                O[(size_t)row * N + col] = (__bf16)acc[i][j][r];
            }
}

// ---------------- GEMM: C[M][N] = A[M][K] * B[N][K]^T (64x64 tile) ------------
template <typename OutT>
__global__ __launch_bounds__(256) void gemm_bt(const __bf16* __restrict__ A,
                                               const __bf16* __restrict__ B,
                                               OutT* __restrict__ C,
                                               int M, int N, int K) {
    __shared__ alignas(16) __bf16 Alds[64][72];
    __shared__ alignas(16) __bf16 Blds[64][72];
    const int tid = threadIdx.x;
    const int lane = tid & 63;
    const int w = tid >> 6;
    const int wr = w >> 1, wc = w & 1;
    const int l15 = lane & 15, lhi = lane >> 4;
    const int m0 = blockIdx.y * 64;
    const int n0 = blockIdx.x * 64;

    f32x4 acc[2][2] = {};

    for (int kt = 0; kt < K; kt += 64) {
#pragma unroll
        for (int i = 0; i < 2; ++i) {
            int slot = tid + i * 256;
            int row = slot >> 3;
            int cb = (slot & 7) * 8;
            *reinterpret_cast<bf16x8*>(&Alds[row][cb]) =
                *reinterpret_cast<const bf16x8*>(&A[(size_t)(m0 + row) * K + kt + cb]);
            *reinterpret_cast<bf16x8*>(&Blds[row][cb]) =
                *reinterpret_cast<const bf16x8*>(&B[(size_t)(n0 + row) * K + kt + cb]);
        }
        __syncthreads();
#pragma unroll
        for (int kk = 0; kk < 2; ++kk) {
            bf16x8 a0 = *reinterpret_cast<const bf16x8*>(&Alds[wr * 32 + l15][kk * 32 + lhi * 8]);
            bf16x8 a1 = *reinterpret_cast<const bf16x8*>(&Alds[wr * 32 + 16 + l15][kk * 32 + lhi * 8]);
            bf16x8 b0 = *reinterpret_cast<const bf16x8*>(&Blds[wc * 32 + l15][kk * 32 + lhi * 8]);
            bf16x8 b1 = *reinterpret_cast<const bf16x8*>(&Blds[wc * 32 + 16 + l15][kk * 32 + lhi * 8]);
            acc[0][0] = MFMA(a0, b0, acc[0][0]);
            acc[0][1] = MFMA(a0, b1, acc[0][1]);
            acc[1][0] = MFMA(a1, b0, acc[1][0]);
            acc[1][1] = MFMA(a1, b1, acc[1][1]);
        }
        __syncthreads();
    }
#pragma unroll
    for (int mb = 0; mb < 2; ++mb)
#pragma unroll
        for (int nb = 0; nb < 2; ++nb)
#pragma unroll
            for (int r = 0; r < 4; ++r) {
                int row = m0 + wr * 32 + mb * 16 + lhi * 4 + r;
                int col = n0 + wc * 32 + nb * 16 + l15;
                C[(size_t)row * N + col] = (OutT)acc[mb][nb][r];
            }
}

// ---------------- causal flash attention (swapped QK^T softmax) ----------------
// grid (16 tile-pairs, 2 batch, 16 heads), block 256 (4 waves x 16 q-rows)
// Q is pre-scaled by 0.125*log2(e) in rope; softmax uses exp2.
__global__ __launch_bounds__(256) void attn_kernel(const __bf16* __restrict__ Q,
                                                   const __bf16* __restrict__ K,
                                                   const __bf16* __restrict__ V,
                                                   __bf16* __restrict__ Y) {
    __shared__ alignas(16) __bf16 Klds[64][72];
    __shared__ alignas(16) __bf16 Vt[64 * 72];   // V^T, k-chunk XOR swizzled
    __shared__ alignas(16) __bf16 Plds[4][16][72];

    const int tid = threadIdx.x;
    const int lane = tid & 63;
    const int w = tid >> 6;
    const int l15 = lane & 15, lhi = lane >> 4;
    const int pb = blockIdx.x;  // 0..15
    const int b = blockIdx.y;
    const int h = blockIdx.z;

    for (int seg = 0; seg < 2; ++seg) {
        const int qt = seg ? (31 - pb) : pb;
        const int q0 = qt * 64;
        const size_t qrow = (size_t)(b * SLEN + q0 + w * 16 + l15) * DIM + h * HD;
        const bf16x8 qf0 = *(const bf16x8*)&Q[qrow + lhi * 8];
        const bf16x8 qf1 = *(const bf16x8*)&Q[qrow + 32 + lhi * 8];

        float m = -1e30f, lsum = 0.f;
        f32x4 accO[4] = {};

        for (int kt = 0; kt <= qt; ++kt) {
            // ---- stage K (row-major) and V (transposed, swizzled) ----
#pragma unroll
            for (int i = 0; i < 2; ++i) {
                int slot = tid + i * 256;
                int krow = slot >> 3;
                int cb = (slot & 7) * 8;
                size_t g = (size_t)(b * SLEN + kt * 64 + krow) * DIM + h * HD + cb;
                *(bf16x8*)&Klds[krow][cb] = *(const bf16x8*)&K[g];
                bf16x8 vv = *(const bf16x8*)&V[g];
#pragma unroll
                for (int jj = 0; jj < 8; ++jj) {
                    int d = cb + jj;
                    int boff = d * 144 + ((((krow >> 3) ^ (d >> 3)) & 7) << 4) + ((krow & 7) << 1);
                    *(__bf16*)((char*)Vt + boff) = vv[jj];
                }
            }
            __syncthreads();

            // ---- S^T = K Q^T : lane owns q = l15, keys nb*16 + lhi*4 + r ----
            f32x4 sT[4];
#pragma unroll
            for (int nb = 0; nb < 4; ++nb) {
                bf16x8 k0 = *(const bf16x8*)&Klds[nb * 16 + l15][lhi * 8];
                bf16x8 k1 = *(const bf16x8*)&Klds[nb * 16 + l15][32 + lhi * 8];
                f32x4 a = {};
                a = MFMA(k0, qf0, a);
                a = MFMA(k1, qf1, a);
                sT[nb] = a;
            }
            if (kt == qt) {  // only the diagonal tile is partially masked
                const int qg = w * 16 + l15;
#pragma unroll
                for (int nb = 0; nb < 4; ++nb)
#pragma unroll
                    for (int r = 0; r < 4; ++r) {
                        int key = nb * 16 + lhi * 4 + r;
                        if (key > qg) sT[nb][r] = -1e30f;
                    }
            }
            // ---- online softmax: 15 in-reg max + 2 shfl ----
            float mx = -1e30f;
#pragma unroll
            for (int nb = 0; nb < 4; ++nb)
#pragma unroll
                for (int r = 0; r < 4; ++r) mx = fmaxf(mx, sT[nb][r]);
            mx = fmaxf(mx, __shfl_xor(mx, 16));
            mx = fmaxf(mx, __shfl_xor(mx, 32));
            const float mnew = fmaxf(m, mx);
            const float corr = exp2f(m - mnew);
            m = mnew;
            float rs = 0.f;
#pragma unroll
            for (int nb = 0; nb < 4; ++nb) {
                bf16x4 pk;
#pragma unroll
                for (int r = 0; r < 4; ++r) {
                    float pv = exp2f(sT[nb][r] - mnew);
                    rs += pv;
                    pk[r] = (__bf16)pv;
                }
                *(bf16x4*)&Plds[w][l15][nb * 16 + lhi * 4] = pk;  // P[q][key], b64
            }
            rs += __shfl_xor(rs, 16);
            rs += __shfl_xor(rs, 32);
            lsum = lsum * corr + rs;
            // rescale accO: its rows are q = lhi*4 + r -> fetch that q's corr
#pragma unroll
            for (int r = 0; r < 4; ++r) {
                float cr = __shfl(corr, lhi * 4 + r);
#pragma unroll
                for (int nd = 0; nd < 4; ++nd) accO[nd][r] *= cr;
            }
            // ---- O += P V ----
#pragma unroll
            for (int nd = 0; nd < 4; ++nd) {
#pragma unroll
                for (int kk = 0; kk < 2; ++kk) {
                    bf16x8 pf = *(const bf16x8*)&Plds[w][l15][kk * 32 + lhi * 8];
                    int d = nd * 16 + l15;
                    int chunk = ((kk * 4 + lhi) ^ (d >> 3)) & 7;
                    bf16x8 vf = *(const bf16x8*)((char*)Vt + d * 144 + chunk * 16);
                    accO[nd] = MFMA(pf, vf, accO[nd]);
                }
            }
            __syncthreads();
        }
        // ---- epilogue: O / l (coalesced: col = nd*16 + l15) ----
        const float inv = 1.0f / lsum;
#pragma unroll
        for (int r = 0; r < 4; ++r) {
            float ir = __shfl(inv, lhi * 4 + r);
#pragma unroll
            for (int nd = 0; nd < 4; ++nd) {
                size_t orow = (size_t)(b * SLEN + q0 + w * 16 + lhi * 4 + r) * DIM + h * HD + nd * 16 + l15;
                Y[orow] = (__bf16)(accO[nd][r] * ir);
            }
        }
    }
}

// ---------------- launcher ----------------
extern "C" void kernel_launch(void* const* d_in, const int* in_sizes, int n_in,
                              void* d_out, int out_size, void* d_ws, size_t ws_size,
                              hipStream_t stream) {
    const float* x = (const float*)d_in[0];
    const float* Wq = (const float*)d_in[1];
    const float* Wk = (const float*)d_in[2];
    const float* Wv = (const float*)d_in[3];
    const float* Wo = (const float*)d_in[4];
    float* out = (float*)d_out;

    const size_t XN = (size_t)4096 * 1024;
    const size_t WN = (size_t)1024 * 1024;

    __bf16* xb = (__bf16*)d_ws;
    __bf16* qb = xb + XN;
    __bf16* kb = qb + XN;
    __bf16* vb = kb + XN;
    __bf16* wqb = vb + XN;
    __bf16* wkb = wqb + WN;
    __bf16* wvb = wkb + WN;
    __bf16* wob = wvb + WN;
    __bf16* yb = xb;  // alias: attn writes y after x's last read (QKV GEMM)

    cvt_bf16<<<XN / 8 / 256, 256, 0, stream>>>(x, xb, (int)XN);
    cvt_bf16<<<WN / 8 / 256, 256, 0, stream>>>(Wq, wqb, (int)WN);
    cvt_bf16<<<WN / 8 / 256, 256, 0, stream>>>(Wk, wkb, (int)WN);
    cvt_bf16<<<WN / 8 / 256, 256, 0, stream>>>(Wv, wvb, (int)WN);
    cvt_bf16<<<WN / 8 / 256, 256, 0, stream>>>(Wo, wob, (int)WN);

    dim3 gq(24, 32);  // 3072/128 x 4096/128
    gemm_qkv<<<gq, 256, 0, stream>>>(xb, wqb, wkb, wvb, qb, kb, vb);

    int pairs = 4096 * (DIM / 2);
    // fold softmax scale (1/8) * log2(e) into Q so attention can use exp2
    rope_kernel<<<(pairs + 255) / 256, 256, 0, stream>>>(qb, 4096, 0.18033688011112042f);
    rope_kernel<<<(pairs + 255) / 256, 256, 0, stream>>>(kb, 4096, 1.0f);

    dim3 ga(16, 2, 16);
    attn_kernel<<<ga, 256, 0, stream>>>(qb, kb, vb, yb);

    dim3 gg(1024 / 64, 4096 / 64);
    gemm_bt<float><<<gg, 256, 0, stream>>>(yb, wob, out, 4096, 1024, 1024);
}

// Round 3
// 158.105 us; speedup vs baseline: 1.9411x; 1.0960x over previous
//
#include <hip/hip_runtime.h>
#include <hip/hip_bf16.h>

typedef __attribute__((ext_vector_type(8))) __bf16 bf16x8;
typedef __attribute__((ext_vector_type(4))) __bf16 bf16x4;
typedef __attribute__((ext_vector_type(4))) float f32x4;

#define DIM 1024
#define SLEN 2048
#define NH 16
#define HD 64

__device__ __forceinline__ f32x4 MFMA(bf16x8 a, bf16x8 b, f32x4 c) {
    return __builtin_amdgcn_mfma_f32_16x16x32_bf16(a, b, c, 0, 0, 0);
}

// ---------------- f32 -> bf16 convert (n % 8 == 0) ----------------
__global__ __launch_bounds__(256) void cvt_bf16(const float* __restrict__ in,
                                                __bf16* __restrict__ out, int n) {
    int i = (blockIdx.x * blockDim.x + threadIdx.x) * 8;
    if (i >= n) return;
    f32x4 a = *reinterpret_cast<const f32x4*>(in + i);
    f32x4 b = *reinterpret_cast<const f32x4*>(in + i + 4);
    bf16x8 o;
#pragma unroll
    for (int j = 0; j < 4; ++j) { o[j] = (__bf16)a[j]; o[j + 4] = (__bf16)b[j]; }
    *reinterpret_cast<bf16x8*>(out + i) = o;
}

// ---------------- RoPE in-place on bf16 [nrows][DIM], with output scale --------
__global__ __launch_bounds__(256) void rope_kernel(__bf16* __restrict__ t, int nrows,
                                                   float scale) {
    int idx = blockIdx.x * blockDim.x + threadIdx.x;
    if (idx >= nrows * (DIM / 2)) return;
    int row = idx >> 9;
    int p = idx & 511;
    int head = p >> 5;
    int j = p & 31;
    int s = row & (SLEN - 1);
    float inv = expf(-0.28782313662425574f * (float)j);
    float angle = (float)s * inv;
    float sn, cs;
    sincosf(angle, &sn, &cs);
    size_t base = (size_t)row * DIM + head * HD + 2 * j;
    float e = (float)t[base], o = (float)t[base + 1];
    t[base] = (__bf16)((e * cs - o * sn) * scale);
    t[base + 1] = (__bf16)((e * sn + o * cs) * scale);
}

// ---------------- fused QKV GEMM: 128x128 tile, BK=64, global_load_lds --------
// Q,K written row-major [token][dim]; V written TRANSPOSED: Vt[(b*16+h)*64+d][s]
__global__ __launch_bounds__(256) void gemm_qkv(const __bf16* __restrict__ X,
                                                const __bf16* __restrict__ Wq,
                                                const __bf16* __restrict__ Wk,
                                                const __bf16* __restrict__ Wv,
                                                __bf16* __restrict__ Qo,
                                                __bf16* __restrict__ Ko,
                                                __bf16* __restrict__ Vt) {
    __shared__ alignas(16) __bf16 Alds[128 * 64];
    __shared__ alignas(16) __bf16 Blds[128 * 64];
    const int tid = threadIdx.x;
    const int lane = tid & 63;
    const int w = tid >> 6;
    const int wr = w >> 1, wc = w & 1;
    const int l15 = lane & 15, lhi = lane >> 4;
    const int m0 = blockIdx.y * 128;
    const int n0g = blockIdx.x * 128;
    const int seg = n0g >> 10;
    const int n0 = n0g & 1023;
    const __bf16* __restrict__ B = seg == 0 ? Wq : seg == 1 ? Wk : Wv;
    const int K = 1024, N = 1024;

    const int lrow = lane >> 3;
    const int lcol = (lane & 7) * 8;

    f32x4 acc[4][4] = {};

    for (int kt = 0; kt < K; kt += 64) {
#pragma unroll
        for (int c = 0; c < 4; ++c) {
            int r0 = c * 32 + w * 8;
            const __bf16* sa = &X[(size_t)(m0 + r0 + lrow) * K + kt + lcol];
            const __bf16* sb = &B[(size_t)(n0 + r0 + lrow) * K + kt + lcol];
            __builtin_amdgcn_global_load_lds((const __attribute__((address_space(1))) void*)sa,
                                             (__attribute__((address_space(3))) void*)&Alds[r0 * 64],
                                             16, 0, 0);
            __builtin_amdgcn_global_load_lds((const __attribute__((address_space(1))) void*)sb,
                                             (__attribute__((address_space(3))) void*)&Blds[r0 * 64],
                                             16, 0, 0);
        }
        __syncthreads();
#pragma unroll
        for (int kk = 0; kk < 2; ++kk) {
            bf16x8 af[4], bfr[4];
#pragma unroll
            for (int i = 0; i < 4; ++i) {
                af[i] = *(const bf16x8*)&Alds[(wr * 64 + i * 16 + l15) * 64 + kk * 32 + lhi * 8];
                bfr[i] = *(const bf16x8*)&Blds[(wc * 64 + i * 16 + l15) * 64 + kk * 32 + lhi * 8];
            }
#pragma unroll
            for (int i = 0; i < 4; ++i)
#pragma unroll
                for (int j = 0; j < 4; ++j)
                    acc[i][j] = MFMA(af[i], bfr[j], acc[i][j]);
        }
        __syncthreads();
    }
    if (seg < 2) {
        __bf16* __restrict__ O = seg == 0 ? Qo : Ko;
#pragma unroll
        for (int i = 0; i < 4; ++i)
#pragma unroll
            for (int j = 0; j < 4; ++j)
#pragma unroll
                for (int r = 0; r < 4; ++r) {
                    int row = m0 + wr * 64 + i * 16 + lhi * 4 + r;
                    int col = n0 + wc * 64 + j * 16 + l15;
                    O[(size_t)row * N + col] = (__bf16)acc[i][j][r];
                }
    } else {
        // V: write transposed Vt[(b*16+h)*64 + d][s], packed over 4 consecutive s
#pragma unroll
        for (int i = 0; i < 4; ++i)
#pragma unroll
            for (int j = 0; j < 4; ++j) {
                int row = m0 + wr * 64 + i * 16 + lhi * 4;  // token base (s), mult of 4
                int col = n0 + wc * 64 + j * 16 + l15;      // dim
                int bb = row >> 11, s = row & 2047;
                int hh = col >> 6, d = col & 63;
                bf16x4 pk;
#pragma unroll
                for (int r = 0; r < 4; ++r) pk[r] = (__bf16)acc[i][j][r];
                *(bf16x4*)&Vt[((size_t)(bb * 16 + hh) * 64 + d) * SLEN + s] = pk;
            }
    }
}

// ---------------- O-projection GEMM: 128x128 tile, f32 out --------------------
__global__ __launch_bounds__(256) void gemm128_f32(const __bf16* __restrict__ A,
                                                   const __bf16* __restrict__ B,
                                                   float* __restrict__ C) {
    __shared__ alignas(16) __bf16 Alds[128 * 64];
    __shared__ alignas(16) __bf16 Blds[128 * 64];
    const int tid = threadIdx.x;
    const int lane = tid & 63;
    const int w = tid >> 6;
    const int wr = w >> 1, wc = w & 1;
    const int l15 = lane & 15, lhi = lane >> 4;
    const int m0 = blockIdx.y * 128;
    const int n0 = blockIdx.x * 128;
    const int K = 1024, N = 1024;

    const int lrow = lane >> 3;
    const int lcol = (lane & 7) * 8;

    f32x4 acc[4][4] = {};

    for (int kt = 0; kt < K; kt += 64) {
#pragma unroll
        for (int c = 0; c < 4; ++c) {
            int r0 = c * 32 + w * 8;
            const __bf16* sa = &A[(size_t)(m0 + r0 + lrow) * K + kt + lcol];
            const __bf16* sb = &B[(size_t)(n0 + r0 + lrow) * K + kt + lcol];
            __builtin_amdgcn_global_load_lds((const __attribute__((address_space(1))) void*)sa,
                                             (__attribute__((address_space(3))) void*)&Alds[r0 * 64],
                                             16, 0, 0);
            __builtin_amdgcn_global_load_lds((const __attribute__((address_space(1))) void*)sb,
                                             (__attribute__((address_space(3))) void*)&Blds[r0 * 64],
                                             16, 0, 0);
        }
        __syncthreads();
#pragma unroll
        for (int kk = 0; kk < 2; ++kk) {
            bf16x8 af[4], bfr[4];
#pragma unroll
            for (int i = 0; i < 4; ++i) {
                af[i] = *(const bf16x8*)&Alds[(wr * 64 + i * 16 + l15) * 64 + kk * 32 + lhi * 8];
                bfr[i] = *(const bf16x8*)&Blds[(wc * 64 + i * 16 + l15) * 64 + kk * 32 + lhi * 8];
            }
#pragma unroll
            for (int i = 0; i < 4; ++i)
#pragma unroll
                for (int j = 0; j < 4; ++j)
                    acc[i][j] = MFMA(af[i], bfr[j], acc[i][j]);
        }
        __syncthreads();
    }
#pragma unroll
    for (int i = 0; i < 4; ++i)
#pragma unroll
        for (int j = 0; j < 4; ++j)
#pragma unroll
            for (int r = 0; r < 4; ++r) {
                int row = m0 + wr * 64 + i * 16 + lhi * 4 + r;
                int col = n0 + wc * 64 + j * 16 + l15;
                C[(size_t)row * N + col] = acc[i][j][r];
            }
}

// ---------------- causal flash attention, O^T form ----------------------------
// 256 blocks x 512 threads (8 waves). Block handles two 128-row q-tiles
// (qt = pb and 15-pb) for one (b,h). K,V staged via global_load_lds with
// source-side XOR swizzle (linear LDS dest + swizzled read). V comes
// pre-transposed from gemm_qkv. PV computed as O^T = V^T P^T so softmax
// stats, rescale, and epilogue are all lane-local (lane owns q = l15).
__global__ __launch_bounds__(512) void attn_kernel(const __bf16* __restrict__ Q,
                                                   const __bf16* __restrict__ K,
                                                   const __bf16* __restrict__ Vt,
                                                   __bf16* __restrict__ Y) {
    __shared__ __bf16 Klds[2][64 * 64];   // [key][d-blocks swizzled]
    __shared__ __bf16 Vlds[2][64 * 64];   // [d][key-blocks swizzled]
    __shared__ __bf16 Plds[8][16][80];    // per-wave P[q][key]

    const int tid = threadIdx.x;
    const int lane = tid & 63;
    const int w = tid >> 6;               // 0..7
    const int l15 = lane & 15, lhi = lane >> 4;
    const int l7 = l15 & 7;

    // XCD-chunked swizzle: XCD x gets 4 consecutive (b,h) -> 2MB K/V, L2-resident
    int id = blockIdx.x;                  // 0..255
    int wg = (id & 7) * 32 + (id >> 3);
    const int pb = wg & 7;                // 0..7 -> q-tiles {pb, 15-pb}
    const int bh = wg >> 3;               // 0..31
    const int b = bh >> 4, h = bh & 15;   // bh == b*16 + h (matches Vt layout)

    // staging: wave w covers rows 8w..8w+7 of the 64x128B tile; lane l ->
    // row 8w + (l>>3), 16B block (l&7); source block = (l&7) ^ (row&7)
    const int srow = (lane >> 3);
    const int scs = (lane & 7) ^ srow;
    const __bf16* Kbase = K + (size_t)b * SLEN * DIM + h * HD;
    const __bf16* Vbase = Vt + (size_t)bh * 64 * SLEN;

    auto stage = [&](int buf, int kt) {
        const __bf16* sk = Kbase + (size_t)(kt * 64 + 8 * w + srow) * DIM + scs * 8;
        const __bf16* sv = Vbase + (size_t)(8 * w + srow) * SLEN + kt * 64 + scs * 8;
        __builtin_amdgcn_global_load_lds((const __attribute__((address_space(1))) void*)sk,
                                         (__attribute__((address_space(3))) void*)&Klds[buf][8 * w * 64],
                                         16, 0, 0);
        __builtin_amdgcn_global_load_lds((const __attribute__((address_space(1))) void*)sv,
                                         (__attribute__((address_space(3))) void*)&Vlds[buf][8 * w * 64],
                                         16, 0, 0);
    };

    for (int seg = 0; seg < 2; ++seg) {
        const int qt = seg ? (15 - pb) : pb;
        const int q0 = qt * 128;
        const int qrow_g = q0 + w * 16 + l15;
        const size_t qbase = (size_t)(b * SLEN + qrow_g) * DIM + h * HD;
        const bf16x8 qf0 = *(const bf16x8*)&Q[qbase + lhi * 8];
        const bf16x8 qf1 = *(const bf16x8*)&Q[qbase + 32 + lhi * 8];

        float m = -1e30f, lsum = 0.f;
        f32x4 acc[4] = {};  // acc[nd][r]: d = nd*16 + lhi*4 + r, q = l15

        const int nkt = 2 * qt + 2;  // kv tiles 0..2qt+1 (nkt even)
        stage(0, 0);
        for (int kt = 0; kt < nkt; ++kt) {
            const int cur = kt & 1;
            __syncthreads();  // drains vmcnt: buf[cur] staged; buf[cur^1] free
            if (kt + 1 < nkt) stage(cur ^ 1, kt + 1);

            // wave-level skip of fully-masked tiles (barrier already done)
            if (kt * 64 > q0 + w * 16 + 15) continue;

            // ---- S^T = K Q^T : lane owns q=l15; keys nb*16 + lhi*4 + r ----
            f32x4 sT[4];
#pragma unroll
            for (int nb = 0; nb < 4; ++nb) {
                const int krow = (nb * 16 + l15) * 64;
                bf16x8 k0 = *(const bf16x8*)&Klds[cur][krow + 8 * ((0 + lhi) ^ l7)];
                bf16x8 k1 = *(const bf16x8*)&Klds[cur][krow + 8 * ((4 + lhi) ^ l7)];
                f32x4 a = {};
                a = MFMA(k0, qf0, a);
                a = MFMA(k1, qf1, a);
                sT[nb] = a;
            }
            if (kt * 64 + 63 > q0 + w * 16) {  // partial-mask tile
#pragma unroll
                for (int nb = 0; nb < 4; ++nb)
#pragma unroll
                    for (int r = 0; r < 4; ++r)
                        if (kt * 64 + nb * 16 + lhi * 4 + r > qrow_g) sT[nb][r] = -1e30f;
            }
            // ---- online softmax (lane-local + 2 shfl over lhi groups) ----
            float mx = -1e30f;
#pragma unroll
            for (int nb = 0; nb < 4; ++nb)
#pragma unroll
                for (int r = 0; r < 4; ++r) mx = fmaxf(mx, sT[nb][r]);
            mx = fmaxf(mx, __shfl_xor(mx, 16));
            mx = fmaxf(mx, __shfl_xor(mx, 32));
            const float mnew = fmaxf(m, mx);
            const float corr = exp2f(m - mnew);
            m = mnew;
            float rs = 0.f;
#pragma unroll
            for (int nb = 0; nb < 4; ++nb) {
                bf16x4 pk;
#pragma unroll
                for (int r = 0; r < 4; ++r) {
                    float pv = exp2f(sT[nb][r] - mnew);
                    rs += pv;
                    pk[r] = (__bf16)pv;
                }
                *(bf16x4*)&Plds[w][l15][nb * 16 + lhi * 4] = pk;
            }
            rs += __shfl_xor(rs, 16);
            rs += __shfl_xor(rs, 32);
            lsum = lsum * corr + rs;
#pragma unroll
            for (int nd = 0; nd < 4; ++nd)
#pragma unroll
                for (int r = 0; r < 4; ++r) acc[nd][r] *= corr;  // lane-local!

            // ---- O^T += V^T P^T : A = V^T frag (vf), B = P^T frag (pf) ----
#pragma unroll
            for (int kk = 0; kk < 2; ++kk) {
                const bf16x8 pf = *(const bf16x8*)&Plds[w][l15][kk * 32 + lhi * 8];
#pragma unroll
                for (int nd = 0; nd < 4; ++nd) {
                    const int vrow = (nd * 16 + l15) * 64;
                    bf16x8 vf = *(const bf16x8*)&Vlds[cur][vrow + 8 * ((kk * 4 + lhi) ^ l7)];
                    acc[nd] = MFMA(vf, pf, acc[nd]);
                }
            }
        }
        // ---- epilogue: lane-local 1/lsum, packed bf16x4 stores ----
        const float inv = 1.0f / lsum;
#pragma unroll
        for (int nd = 0; nd < 4; ++nd) {
            bf16x4 o;
#pragma unroll
            for (int r = 0; r < 4; ++r) o[r] = (__bf16)(acc[nd][r] * inv);
            *(bf16x4*)&Y[(size_t)(b * SLEN + qrow_g) * DIM + h * HD + nd * 16 + lhi * 4] = o;
        }
    }
}

// ---------------- launcher ----------------
extern "C" void kernel_launch(void* const* d_in, const int* in_sizes, int n_in,
                              void* d_out, int out_size, void* d_ws, size_t ws_size,
                              hipStream_t stream) {
    const float* x = (const float*)d_in[0];
    const float* Wq = (const float*)d_in[1];
    const float* Wk = (const float*)d_in[2];
    const float* Wv = (const float*)d_in[3];
    const float* Wo = (const float*)d_in[4];
    float* out = (float*)d_out;

    const size_t XN = (size_t)4096 * 1024;
    const size_t WN = (size_t)1024 * 1024;

    __bf16* xb = (__bf16*)d_ws;
    __bf16* qb = xb + XN;
    __bf16* kb = qb + XN;
    __bf16* vtb = kb + XN;   // transposed V: [(b*16+h)*64 + d][SLEN]
    __bf16* wqb = vtb + XN;
    __bf16* wkb = wqb + WN;
    __bf16* wvb = wkb + WN;
    __bf16* wob = wvb + WN;
    __bf16* yb = xb;  // alias: attn writes y after x's last read (QKV GEMM)

    cvt_bf16<<<XN / 8 / 256, 256, 0, stream>>>(x, xb, (int)XN);
    cvt_bf16<<<WN / 8 / 256, 256, 0, stream>>>(Wq, wqb, (int)WN);
    cvt_bf16<<<WN / 8 / 256, 256, 0, stream>>>(Wk, wkb, (int)WN);
    cvt_bf16<<<WN / 8 / 256, 256, 0, stream>>>(Wv, wvb, (int)WN);
    cvt_bf16<<<WN / 8 / 256, 256, 0, stream>>>(Wo, wob, (int)WN);

    dim3 gq(24, 32);  // 3072/128 x 4096/128
    gemm_qkv<<<gq, 256, 0, stream>>>(xb, wqb, wkb, wvb, qb, kb, vtb);

    int pairs = 4096 * (DIM / 2);
    // fold softmax scale (1/8) * log2(e) into Q so attention can use exp2
    rope_kernel<<<(pairs + 255) / 256, 256, 0, stream>>>(qb, 4096, 0.18033688011112042f);
    rope_kernel<<<(pairs + 255) / 256, 256, 0, stream>>>(kb, 4096, 1.0f);

    attn_kernel<<<256, 512, 0, stream>>>(qb, kb, vtb, yb);

    dim3 go(8, 32);
    gemm128_f32<<<go, 256, 0, stream>>>(yb, wob, out);
}

// Round 4
// 145.833 us; speedup vs baseline: 2.1044x; 1.0842x over previous
//
#include <hip/hip_runtime.h>
#include <hip/hip_bf16.h>

typedef __attribute__((ext_vector_type(8))) __bf16 bf16x8;
typedef __attribute__((ext_vector_type(4))) __bf16 bf16x4;
typedef __attribute__((ext_vector_type(4))) float f32x4;

#define DIM 1024
#define SLEN 2048
#define NH 16
#define HD 64

__device__ __forceinline__ f32x4 MFMA(bf16x8 a, bf16x8 b, f32x4 c) {
    return __builtin_amdgcn_mfma_f32_16x16x32_bf16(a, b, c, 0, 0, 0);
}

// ---------------- f32 -> bf16 convert (n % 8 == 0) ----------------
__global__ __launch_bounds__(256) void cvt_bf16(const float* __restrict__ in,
                                                __bf16* __restrict__ out, int n) {
    int i = (blockIdx.x * blockDim.x + threadIdx.x) * 8;
    if (i >= n) return;
    f32x4 a = *reinterpret_cast<const f32x4*>(in + i);
    f32x4 b = *reinterpret_cast<const f32x4*>(in + i + 4);
    bf16x8 o;
#pragma unroll
    for (int j = 0; j < 4; ++j) { o[j] = (__bf16)a[j]; o[j + 4] = (__bf16)b[j]; }
    *reinterpret_cast<bf16x8*>(out + i) = o;
}

// 4 weight matrices in one launch (blockIdx.y selects)
__global__ __launch_bounds__(256) void cvt_w4(const float* __restrict__ w0,
                                              const float* __restrict__ w1,
                                              const float* __restrict__ w2,
                                              const float* __restrict__ w3,
                                              __bf16* __restrict__ o0,
                                              __bf16* __restrict__ o1,
                                              __bf16* __restrict__ o2,
                                              __bf16* __restrict__ o3) {
    int s = blockIdx.y;
    const float* in = s == 0 ? w0 : s == 1 ? w1 : s == 2 ? w2 : w3;
    __bf16* out = s == 0 ? o0 : s == 1 ? o1 : s == 2 ? o2 : o3;
    int i = (blockIdx.x * blockDim.x + threadIdx.x) * 8;
    f32x4 a = *reinterpret_cast<const f32x4*>(in + i);
    f32x4 b = *reinterpret_cast<const f32x4*>(in + i + 4);
    bf16x8 o;
#pragma unroll
    for (int j = 0; j < 4; ++j) { o[j] = (__bf16)a[j]; o[j + 4] = (__bf16)b[j]; }
    *reinterpret_cast<bf16x8*>(out + i) = o;
}

// ---------------- RoPE on q and k in one launch --------------------------------
__global__ __launch_bounds__(256) void rope2(__bf16* __restrict__ q,
                                             __bf16* __restrict__ k) {
    __bf16* t = blockIdx.y == 0 ? q : k;
    // fold softmax scale (1/8)*log2(e) into q so attention can use exp2
    const float scale = blockIdx.y == 0 ? 0.18033688011112042f : 1.0f;
    int idx = blockIdx.x * blockDim.x + threadIdx.x;
    int row = idx >> 9;
    int p = idx & 511;
    int head = p >> 5;
    int j = p & 31;
    int s = row & (SLEN - 1);
    float inv = expf(-0.28782313662425574f * (float)j);
    float angle = (float)s * inv;
    float sn, cs;
    sincosf(angle, &sn, &cs);
    size_t base = (size_t)row * DIM + head * HD + 2 * j;
    float e = (float)t[base], o = (float)t[base + 1];
    t[base] = (__bf16)((e * cs - o * sn) * scale);
    t[base + 1] = (__bf16)((e * sn + o * cs) * scale);
}

// ---------------- fused QKV GEMM: 128x128 tile, BK=64, swizzled LDS -----------
// Q,K row-major [token][dim]; V TRANSPOSED: Vt[(b*16+h)*64+d][s]
__global__ __launch_bounds__(256) void gemm_qkv(const __bf16* __restrict__ X,
                                                const __bf16* __restrict__ Wq,
                                                const __bf16* __restrict__ Wk,
                                                const __bf16* __restrict__ Wv,
                                                __bf16* __restrict__ Qo,
                                                __bf16* __restrict__ Ko,
                                                __bf16* __restrict__ Vt) {
    __shared__ alignas(16) __bf16 Alds[128 * 64];
    __shared__ alignas(16) __bf16 Blds[128 * 64];
    const int tid = threadIdx.x;
    const int lane = tid & 63;
    const int w = tid >> 6;
    const int wr = w >> 1, wc = w & 1;
    const int l15 = lane & 15, lhi = lane >> 4;
    const int l7 = l15 & 7;
    const int m0 = blockIdx.y * 128;
    const int n0g = blockIdx.x * 128;
    const int seg = n0g >> 10;
    const int n0 = n0g & 1023;
    const __bf16* __restrict__ B = seg == 0 ? Wq : seg == 1 ? Wk : Wv;
    const int K = 1024, N = 1024;

    const int lrow = lane >> 3;                 // 0..7
    const int scol = ((lane & 7) ^ lrow) * 8;   // source-side XOR swizzle

    f32x4 acc[4][4] = {};

    for (int kt = 0; kt < K; kt += 64) {
#pragma unroll
        for (int c = 0; c < 4; ++c) {
            int r0 = c * 32 + w * 8;
            const __bf16* sa = &X[(size_t)(m0 + r0 + lrow) * K + kt + scol];
            const __bf16* sb = &B[(size_t)(n0 + r0 + lrow) * K + kt + scol];
            __builtin_amdgcn_global_load_lds((const __attribute__((address_space(1))) void*)sa,
                                             (__attribute__((address_space(3))) void*)&Alds[r0 * 64],
                                             16, 0, 0);
            __builtin_amdgcn_global_load_lds((const __attribute__((address_space(1))) void*)sb,
                                             (__attribute__((address_space(3))) void*)&Blds[r0 * 64],
                                             16, 0, 0);
        }
        __syncthreads();
#pragma unroll
        for (int kk = 0; kk < 2; ++kk) {
            bf16x8 af[4], bfr[4];
#pragma unroll
            for (int i = 0; i < 4; ++i) {
                af[i] = *(const bf16x8*)&Alds[(wr * 64 + i * 16 + l15) * 64 + 8 * ((kk * 4 + lhi) ^ l7)];
                bfr[i] = *(const bf16x8*)&Blds[(wc * 64 + i * 16 + l15) * 64 + 8 * ((kk * 4 + lhi) ^ l7)];
            }
            __builtin_amdgcn_s_setprio(1);
#pragma unroll
            for (int i = 0; i < 4; ++i)
#pragma unroll
                for (int j = 0; j < 4; ++j)
                    acc[i][j] = MFMA(af[i], bfr[j], acc[i][j]);
            __builtin_amdgcn_s_setprio(0);
        }
        __syncthreads();
    }
    if (seg < 2) {
        __bf16* __restrict__ O = seg == 0 ? Qo : Ko;
#pragma unroll
        for (int i = 0; i < 4; ++i)
#pragma unroll
            for (int j = 0; j < 4; ++j)
#pragma unroll
                for (int r = 0; r < 4; ++r) {
                    int row = m0 + wr * 64 + i * 16 + lhi * 4 + r;
                    int col = n0 + wc * 64 + j * 16 + l15;
                    O[(size_t)row * N + col] = (__bf16)acc[i][j][r];
                }
    } else {
        // V: write transposed Vt[(b*16+h)*64 + d][s], packed over 4 consecutive s
#pragma unroll
        for (int i = 0; i < 4; ++i)
#pragma unroll
            for (int j = 0; j < 4; ++j) {
                int row = m0 + wr * 64 + i * 16 + lhi * 4;  // token base, mult of 4
                int col = n0 + wc * 64 + j * 16 + l15;      // dim
                int bb = row >> 11, s = row & 2047;
                int hh = col >> 6, d = col & 63;
                bf16x4 pk;
#pragma unroll
                for (int r = 0; r < 4; ++r) pk[r] = (__bf16)acc[i][j][r];
                *(bf16x4*)&Vt[((size_t)(bb * 16 + hh) * 64 + d) * SLEN + s] = pk;
            }
    }
}

// ---------------- O-projection GEMM: 128x128 tile, f32 out, swizzled LDS ------
__global__ __launch_bounds__(256) void gemm128_f32(const __bf16* __restrict__ A,
                                                   const __bf16* __restrict__ B,
                                                   float* __restrict__ C) {
    __shared__ alignas(16) __bf16 Alds[128 * 64];
    __shared__ alignas(16) __bf16 Blds[128 * 64];
    const int tid = threadIdx.x;
    const int lane = tid & 63;
    const int w = tid >> 6;
    const int wr = w >> 1, wc = w & 1;
    const int l15 = lane & 15, lhi = lane >> 4;
    const int l7 = l15 & 7;
    const int m0 = blockIdx.y * 128;
    const int n0 = blockIdx.x * 128;
    const int K = 1024, N = 1024;

    const int lrow = lane >> 3;
    const int scol = ((lane & 7) ^ lrow) * 8;

    f32x4 acc[4][4] = {};

    for (int kt = 0; kt < K; kt += 64) {
#pragma unroll
        for (int c = 0; c < 4; ++c) {
            int r0 = c * 32 + w * 8;
            const __bf16* sa = &A[(size_t)(m0 + r0 + lrow) * K + kt + scol];
            const __bf16* sb = &B[(size_t)(n0 + r0 + lrow) * K + kt + scol];
            __builtin_amdgcn_global_load_lds((const __attribute__((address_space(1))) void*)sa,
                                             (__attribute__((address_space(3))) void*)&Alds[r0 * 64],
                                             16, 0, 0);
            __builtin_amdgcn_global_load_lds((const __attribute__((address_space(1))) void*)sb,
                                             (__attribute__((address_space(3))) void*)&Blds[r0 * 64],
                                             16, 0, 0);
        }
        __syncthreads();
#pragma unroll
        for (int kk = 0; kk < 2; ++kk) {
            bf16x8 af[4], bfr[4];
#pragma unroll
            for (int i = 0; i < 4; ++i) {
                af[i] = *(const bf16x8*)&Alds[(wr * 64 + i * 16 + l15) * 64 + 8 * ((kk * 4 + lhi) ^ l7)];
                bfr[i] = *(const bf16x8*)&Blds[(wc * 64 + i * 16 + l15) * 64 + 8 * ((kk * 4 + lhi) ^ l7)];
            }
            __builtin_amdgcn_s_setprio(1);
#pragma unroll
            for (int i = 0; i < 4; ++i)
#pragma unroll
                for (int j = 0; j < 4; ++j)
                    acc[i][j] = MFMA(af[i], bfr[j], acc[i][j]);
            __builtin_amdgcn_s_setprio(0);
        }
        __syncthreads();
    }
#pragma unroll
    for (int i = 0; i < 4; ++i)
#pragma unroll
        for (int j = 0; j < 4; ++j)
#pragma unroll
            for (int r = 0; r < 4; ++r) {
                int row = m0 + wr * 64 + i * 16 + lhi * 4 + r;
                int col = n0 + wc * 64 + j * 16 + l15;
                C[(size_t)row * N + col] = acc[i][j][r];
            }
}

// ---------------- causal flash attention, O^T form ----------------------------
// 512 blocks x 512 threads (8 waves): one 128-row q-tile per block, 2 blocks/CU.
// Per-XCD bh-chunking (L2-resident K/V) + longest-tile-first within each stream.
__global__ __launch_bounds__(512) void attn_kernel(const __bf16* __restrict__ Q,
                                                   const __bf16* __restrict__ K,
                                                   const __bf16* __restrict__ Vt,
                                                   __bf16* __restrict__ Y) {
    __shared__ __bf16 Klds[2][64 * 64];   // [key][d-blocks swizzled]
    __shared__ __bf16 Vlds[2][64 * 64];   // [d][key-blocks swizzled]
    __shared__ __bf16 Plds[8][16][80];    // per-wave P[q][key]

    const int tid = threadIdx.x;
    const int lane = tid & 63;
    const int w = tid >> 6;               // 0..7
    const int l15 = lane & 15, lhi = lane >> 4;
    const int l7 = l15 & 7;

    // XCD x serves bh in [4x,4x+4) (2MB K/V -> L2-resident); qt descending (LPT)
    const int id = blockIdx.x;            // 0..511
    const int wg = (id & 7) * 64 + (id >> 3);
    const int bh = wg >> 4;               // 0..31
    const int qt = 15 - (wg & 15);        // 15..0 within each stream
    const int b = bh >> 4, h = bh & 15;

    const int srow = (lane >> 3);
    const int scs = (lane & 7) ^ srow;
    const __bf16* Kbase = K + (size_t)b * SLEN * DIM + h * HD;
    const __bf16* Vbase = Vt + (size_t)bh * 64 * SLEN;

    auto stage = [&](int buf, int kt) {
        const __bf16* sk = Kbase + (size_t)(kt * 64 + 8 * w + srow) * DIM + scs * 8;
        const __bf16* sv = Vbase + (size_t)(8 * w + srow) * SLEN + kt * 64 + scs * 8;
        __builtin_amdgcn_global_load_lds((const __attribute__((address_space(1))) void*)sk,
                                         (__attribute__((address_space(3))) void*)&Klds[buf][8 * w * 64],
                                         16, 0, 0);
        __builtin_amdgcn_global_load_lds((const __attribute__((address_space(1))) void*)sv,
                                         (__attribute__((address_space(3))) void*)&Vlds[buf][8 * w * 64],
                                         16, 0, 0);
    };

    const int q0 = qt * 128;
    const int qrow_g = q0 + w * 16 + l15;
    const size_t qbase = (size_t)(b * SLEN + qrow_g) * DIM + h * HD;
    const bf16x8 qf0 = *(const bf16x8*)&Q[qbase + lhi * 8];
    const bf16x8 qf1 = *(const bf16x8*)&Q[qbase + 32 + lhi * 8];

    float m = -1e30f, lsum = 0.f;
    f32x4 acc[4] = {};  // acc[nd][r]: d = nd*16 + lhi*4 + r, q = l15

    const int nkt = 2 * qt + 2;  // kv tiles 0..2qt+1
    stage(0, 0);
    for (int kt = 0; kt < nkt; ++kt) {
        const int cur = kt & 1;
        __syncthreads();  // drains vmcnt: buf[cur] staged; buf[cur^1] free
        if (kt + 1 < nkt) stage(cur ^ 1, kt + 1);

        // wave-level skip of fully-masked tiles (barrier already done)
        if (kt * 64 > q0 + w * 16 + 15) continue;

        // ---- S^T = K Q^T : lane owns q=l15; keys nb*16 + lhi*4 + r ----
        f32x4 sT[4];
        __builtin_amdgcn_s_setprio(1);
#pragma unroll
        for (int nb = 0; nb < 4; ++nb) {
            const int krow = (nb * 16 + l15) * 64;
            bf16x8 k0 = *(const bf16x8*)&Klds[cur][krow + 8 * ((0 + lhi) ^ l7)];
            bf16x8 k1 = *(const bf16x8*)&Klds[cur][krow + 8 * ((4 + lhi) ^ l7)];
            f32x4 a = {};
            a = MFMA(k0, qf0, a);
            a = MFMA(k1, qf1, a);
            sT[nb] = a;
        }
        __builtin_amdgcn_s_setprio(0);
        if (kt * 64 + 63 > q0 + w * 16) {  // partial-mask tile
#pragma unroll
            for (int nb = 0; nb < 4; ++nb)
#pragma unroll
                for (int r = 0; r < 4; ++r)
                    if (kt * 64 + nb * 16 + lhi * 4 + r > qrow_g) sT[nb][r] = -1e30f;
        }
        // ---- online softmax (lane-local + 2 shfl over lhi groups) ----
        float mx = -1e30f;
#pragma unroll
        for (int nb = 0; nb < 4; ++nb)
#pragma unroll
            for (int r = 0; r < 4; ++r) mx = fmaxf(mx, sT[nb][r]);
        mx = fmaxf(mx, __shfl_xor(mx, 16));
        mx = fmaxf(mx, __shfl_xor(mx, 32));
        // defer-max (T13): skip rescale while max growth <= 8 (exp2 units)
        if (!__all(mx <= m + 8.0f)) {
            const float mnew = fmaxf(m, mx);
            const float corr = exp2f(m - mnew);
            m = mnew;
            lsum *= corr;
#pragma unroll
            for (int nd = 0; nd < 4; ++nd)
#pragma unroll
                for (int r = 0; r < 4; ++r) acc[nd][r] *= corr;
        }
        float rs = 0.f;
#pragma unroll
        for (int nb = 0; nb < 4; ++nb) {
            bf16x4 pk;
#pragma unroll
            for (int r = 0; r < 4; ++r) {
                float pv = exp2f(sT[nb][r] - m);
                rs += pv;
                pk[r] = (__bf16)pv;
            }
            *(bf16x4*)&Plds[w][l15][nb * 16 + lhi * 4] = pk;
        }
        rs += __shfl_xor(rs, 16);
        rs += __shfl_xor(rs, 32);
        lsum += rs;

        // ---- O^T += V^T P^T : A = V^T frag, B = P^T frag ----
        __builtin_amdgcn_s_setprio(1);
#pragma unroll
        for (int kk = 0; kk < 2; ++kk) {
            const bf16x8 pf = *(const bf16x8*)&Plds[w][l15][kk * 32 + lhi * 8];
#pragma unroll
            for (int nd = 0; nd < 4; ++nd) {
                const int vrow = (nd * 16 + l15) * 64;
                bf16x8 vf = *(const bf16x8*)&Vlds[cur][vrow + 8 * ((kk * 4 + lhi) ^ l7)];
                acc[nd] = MFMA(vf, pf, acc[nd]);
            }
        }
        __builtin_amdgcn_s_setprio(0);
    }
    // ---- epilogue: lane-local 1/lsum, packed bf16x4 stores ----
    const float inv = 1.0f / lsum;
#pragma unroll
    for (int nd = 0; nd < 4; ++nd) {
        bf16x4 o;
#pragma unroll
        for (int r = 0; r < 4; ++r) o[r] = (__bf16)(acc[nd][r] * inv);
        *(bf16x4*)&Y[(size_t)(b * SLEN + qrow_g) * DIM + h * HD + nd * 16 + lhi * 4] = o;
    }
}

// ---------------- launcher ----------------
extern "C" void kernel_launch(void* const* d_in, const int* in_sizes, int n_in,
                              void* d_out, int out_size, void* d_ws, size_t ws_size,
                              hipStream_t stream) {
    const float* x = (const float*)d_in[0];
    const float* Wq = (const float*)d_in[1];
    const float* Wk = (const float*)d_in[2];
    const float* Wv = (const float*)d_in[3];
    const float* Wo = (const float*)d_in[4];
    float* out = (float*)d_out;

    const size_t XN = (size_t)4096 * 1024;
    const size_t WN = (size_t)1024 * 1024;

    __bf16* xb = (__bf16*)d_ws;
    __bf16* qb = xb + XN;
    __bf16* kb = qb + XN;
    __bf16* vtb = kb + XN;   // transposed V: [(b*16+h)*64 + d][SLEN]
    __bf16* wqb = vtb + XN;
    __bf16* wkb = wqb + WN;
    __bf16* wvb = wkb + WN;
    __bf16* wob = wvb + WN;
    __bf16* yb = xb;  // alias: attn writes y after x's last read (QKV GEMM)

    cvt_bf16<<<XN / 8 / 256, 256, 0, stream>>>(x, xb, (int)XN);
    dim3 gw(WN / 8 / 256, 4);
    cvt_w4<<<gw, 256, 0, stream>>>(Wq, Wk, Wv, Wo, wqb, wkb, wvb, wob);

    dim3 gq(24, 32);  // 3072/128 x 4096/128
    gemm_qkv<<<gq, 256, 0, stream>>>(xb, wqb, wkb, wvb, qb, kb, vtb);

    int pairs = 4096 * (DIM / 2);
    dim3 gr(pairs / 256, 2);
    rope2<<<gr, 256, 0, stream>>>(qb, kb);

    attn_kernel<<<512, 512, 0, stream>>>(qb, kb, vtb, yb);

    dim3 go(8, 32);
    gemm128_f32<<<go, 256, 0, stream>>>(yb, wob, out);
}

// Round 5
// 118.730 us; speedup vs baseline: 2.5848x; 1.2283x over previous
//
#include <hip/hip_runtime.h>
#include <hip/hip_bf16.h>

typedef __attribute__((ext_vector_type(8))) __bf16 bf16x8;
typedef __attribute__((ext_vector_type(4))) __bf16 bf16x4;
typedef __attribute__((ext_vector_type(4))) float f32x4;

#define DIM 1024
#define SLEN 2048
#define NH 16
#define HD 64

__device__ __forceinline__ f32x4 MFMA(bf16x8 a, bf16x8 b, f32x4 c) {
    return __builtin_amdgcn_mfma_f32_16x16x32_bf16(a, b, c, 0, 0, 0);
}

// ---------------- f32 -> bf16 convert (n % 8 == 0) ----------------
__global__ __launch_bounds__(256) void cvt_bf16(const float* __restrict__ in,
                                                __bf16* __restrict__ out, int n) {
    int i = (blockIdx.x * blockDim.x + threadIdx.x) * 8;
    if (i >= n) return;
    f32x4 a = *reinterpret_cast<const f32x4*>(in + i);
    f32x4 b = *reinterpret_cast<const f32x4*>(in + i + 4);
    bf16x8 o;
#pragma unroll
    for (int j = 0; j < 4; ++j) { o[j] = (__bf16)a[j]; o[j + 4] = (__bf16)b[j]; }
    *reinterpret_cast<bf16x8*>(out + i) = o;
}

// 4 weight matrices in one launch (blockIdx.y selects)
__global__ __launch_bounds__(256) void cvt_w4(const float* __restrict__ w0,
                                              const float* __restrict__ w1,
                                              const float* __restrict__ w2,
                                              const float* __restrict__ w3,
                                              __bf16* __restrict__ o0,
                                              __bf16* __restrict__ o1,
                                              __bf16* __restrict__ o2,
                                              __bf16* __restrict__ o3) {
    int s = blockIdx.y;
    const float* in = s == 0 ? w0 : s == 1 ? w1 : s == 2 ? w2 : w3;
    __bf16* out = s == 0 ? o0 : s == 1 ? o1 : s == 2 ? o2 : o3;
    int i = (blockIdx.x * blockDim.x + threadIdx.x) * 8;
    f32x4 a = *reinterpret_cast<const f32x4*>(in + i);
    f32x4 b = *reinterpret_cast<const f32x4*>(in + i + 4);
    bf16x8 o;
#pragma unroll
    for (int j = 0; j < 4; ++j) { o[j] = (__bf16)a[j]; o[j + 4] = (__bf16)b[j]; }
    *reinterpret_cast<bf16x8*>(out + i) = o;
}

// ---------------- RoPE on q and k in one launch --------------------------------
__global__ __launch_bounds__(256) void rope2(__bf16* __restrict__ q,
                                             __bf16* __restrict__ k) {
    __bf16* t = blockIdx.y == 0 ? q : k;
    // fold softmax scale (1/8)*log2(e) into q so attention can use exp2
    const float scale = blockIdx.y == 0 ? 0.18033688011112042f : 1.0f;
    int idx = blockIdx.x * blockDim.x + threadIdx.x;
    int row = idx >> 9;
    int p = idx & 511;
    int head = p >> 5;
    int j = p & 31;
    int s = row & (SLEN - 1);
    float inv = expf(-0.28782313662425574f * (float)j);
    float angle = (float)s * inv;
    float sn, cs;
    sincosf(angle, &sn, &cs);
    size_t base = (size_t)row * DIM + head * HD + 2 * j;
    float e = (float)t[base], o = (float)t[base + 1];
    t[base] = (__bf16)((e * cs - o * sn) * scale);
    t[base + 1] = (__bf16)((e * sn + o * cs) * scale);
}

// ---------------- fused QKV GEMM: 128x128 tile, BK=64, swizzled LDS -----------
// Q,K row-major [token][dim]; V TRANSPOSED: Vt[(b*16+h)*64+d][s]
__global__ __launch_bounds__(256) void gemm_qkv(const __bf16* __restrict__ X,
                                                const __bf16* __restrict__ Wq,
                                                const __bf16* __restrict__ Wk,
                                                const __bf16* __restrict__ Wv,
                                                __bf16* __restrict__ Qo,
                                                __bf16* __restrict__ Ko,
                                                __bf16* __restrict__ Vt) {
    __shared__ alignas(16) __bf16 Alds[128 * 64];
    __shared__ alignas(16) __bf16 Blds[128 * 64];
    const int tid = threadIdx.x;
    const int lane = tid & 63;
    const int w = tid >> 6;
    const int wr = w >> 1, wc = w & 1;
    const int l15 = lane & 15, lhi = lane >> 4;
    const int l7 = l15 & 7;
    const int m0 = blockIdx.y * 128;
    const int n0g = blockIdx.x * 128;
    const int seg = n0g >> 10;
    const int n0 = n0g & 1023;
    const __bf16* __restrict__ B = seg == 0 ? Wq : seg == 1 ? Wk : Wv;
    const int K = 1024, N = 1024;

    const int lrow = lane >> 3;                 // 0..7
    const int scol = ((lane & 7) ^ lrow) * 8;   // source-side XOR swizzle

    f32x4 acc[4][4] = {};

    for (int kt = 0; kt < K; kt += 64) {
#pragma unroll
        for (int c = 0; c < 4; ++c) {
            int r0 = c * 32 + w * 8;
            const __bf16* sa = &X[(size_t)(m0 + r0 + lrow) * K + kt + scol];
            const __bf16* sb = &B[(size_t)(n0 + r0 + lrow) * K + kt + scol];
            __builtin_amdgcn_global_load_lds((const __attribute__((address_space(1))) void*)sa,
                                             (__attribute__((address_space(3))) void*)&Alds[r0 * 64],
                                             16, 0, 0);
            __builtin_amdgcn_global_load_lds((const __attribute__((address_space(1))) void*)sb,
                                             (__attribute__((address_space(3))) void*)&Blds[r0 * 64],
                                             16, 0, 0);
        }
        __syncthreads();
#pragma unroll
        for (int kk = 0; kk < 2; ++kk) {
            bf16x8 af[4], bfr[4];
#pragma unroll
            for (int i = 0; i < 4; ++i) {
                af[i] = *(const bf16x8*)&Alds[(wr * 64 + i * 16 + l15) * 64 + 8 * ((kk * 4 + lhi) ^ l7)];
                bfr[i] = *(const bf16x8*)&Blds[(wc * 64 + i * 16 + l15) * 64 + 8 * ((kk * 4 + lhi) ^ l7)];
            }
            __builtin_amdgcn_s_setprio(1);
#pragma unroll
            for (int i = 0; i < 4; ++i)
#pragma unroll
                for (int j = 0; j < 4; ++j)
                    acc[i][j] = MFMA(af[i], bfr[j], acc[i][j]);
            __builtin_amdgcn_s_setprio(0);
        }
        __syncthreads();
    }
    if (seg < 2) {
        __bf16* __restrict__ O = seg == 0 ? Qo : Ko;
#pragma unroll
        for (int i = 0; i < 4; ++i)
#pragma unroll
            for (int j = 0; j < 4; ++j)
#pragma unroll
                for (int r = 0; r < 4; ++r) {
                    int row = m0 + wr * 64 + i * 16 + lhi * 4 + r;
                    int col = n0 + wc * 64 + j * 16 + l15;
                    O[(size_t)row * N + col] = (__bf16)acc[i][j][r];
                }
    } else {
        // V: write transposed Vt[(b*16+h)*64 + d][s], packed over 4 consecutive s
#pragma unroll
        for (int i = 0; i < 4; ++i)
#pragma unroll
            for (int j = 0; j < 4; ++j) {
                int row = m0 + wr * 64 + i * 16 + lhi * 4;  // token base, mult of 4
                int col = n0 + wc * 64 + j * 16 + l15;      // dim
                int bb = row >> 11, s = row & 2047;
                int hh = col >> 6, d = col & 63;
                bf16x4 pk;
#pragma unroll
                for (int r = 0; r < 4; ++r) pk[r] = (__bf16)acc[i][j][r];
                *(bf16x4*)&Vt[((size_t)(bb * 16 + hh) * 64 + d) * SLEN + s] = pk;
            }
    }
}

// ---------------- O-projection GEMM: 64x128 tile, f32 out, 512 blocks ---------
__global__ __launch_bounds__(256) void gemm_o(const __bf16* __restrict__ A,
                                              const __bf16* __restrict__ B,
                                              float* __restrict__ C) {
    __shared__ alignas(16) __bf16 Alds[64 * 64];
    __shared__ alignas(16) __bf16 Blds[128 * 64];
    const int tid = threadIdx.x;
    const int lane = tid & 63;
    const int w = tid >> 6;
    const int wr = w >> 1, wc = w & 1;
    const int l15 = lane & 15, lhi = lane >> 4;
    const int l7 = l15 & 7;
    const int m0 = blockIdx.y * 64;
    const int n0 = blockIdx.x * 128;
    const int K = 1024, N = 1024;

    const int lrow = lane >> 3;
    const int scol = ((lane & 7) ^ lrow) * 8;

    f32x4 acc[2][4] = {};

    for (int kt = 0; kt < K; kt += 64) {
#pragma unroll
        for (int c = 0; c < 2; ++c) {
            int r0 = c * 32 + w * 8;
            const __bf16* sa = &A[(size_t)(m0 + r0 + lrow) * K + kt + scol];
            __builtin_amdgcn_global_load_lds((const __attribute__((address_space(1))) void*)sa,
                                             (__attribute__((address_space(3))) void*)&Alds[r0 * 64],
                                             16, 0, 0);
        }
#pragma unroll
        for (int c = 0; c < 4; ++c) {
            int r0 = c * 32 + w * 8;
            const __bf16* sb = &B[(size_t)(n0 + r0 + lrow) * K + kt + scol];
            __builtin_amdgcn_global_load_lds((const __attribute__((address_space(1))) void*)sb,
                                             (__attribute__((address_space(3))) void*)&Blds[r0 * 64],
                                             16, 0, 0);
        }
        __syncthreads();
#pragma unroll
        for (int kk = 0; kk < 2; ++kk) {
            bf16x8 af[2], bfr[4];
#pragma unroll
            for (int i = 0; i < 2; ++i)
                af[i] = *(const bf16x8*)&Alds[(wr * 32 + i * 16 + l15) * 64 + 8 * ((kk * 4 + lhi) ^ l7)];
#pragma unroll
            for (int j = 0; j < 4; ++j)
                bfr[j] = *(const bf16x8*)&Blds[(wc * 64 + j * 16 + l15) * 64 + 8 * ((kk * 4 + lhi) ^ l7)];
            __builtin_amdgcn_s_setprio(1);
#pragma unroll
            for (int i = 0; i < 2; ++i)
#pragma unroll
                for (int j = 0; j < 4; ++j)
                    acc[i][j] = MFMA(af[i], bfr[j], acc[i][j]);
            __builtin_amdgcn_s_setprio(0);
        }
        __syncthreads();
    }
#pragma unroll
    for (int i = 0; i < 2; ++i)
#pragma unroll
        for (int j = 0; j < 4; ++j)
#pragma unroll
            for (int r = 0; r < 4; ++r) {
                int row = m0 + wr * 32 + i * 16 + lhi * 4 + r;
                int col = n0 + wc * 64 + j * 16 + l15;
                C[(size_t)row * N + col] = acc[i][j][r];
            }
}

// ---------------- causal flash attention, O^T form ----------------------------
// 1024 blocks x 256 threads (4 waves): one 64-row q-tile per block, 3 blocks/CU.
// Per-XCD bh-chunking (L2-resident K/V); qt descending across 4 bh streams
// (LPT with backfill queue). Lane owns q = l15; all softmax stats lane-local.
__global__ __launch_bounds__(256) void attn_kernel(const __bf16* __restrict__ Q,
                                                   const __bf16* __restrict__ K,
                                                   const __bf16* __restrict__ Vt,
                                                   __bf16* __restrict__ Y) {
    __shared__ __bf16 Klds[2][64 * 64];   // [key][d-blocks swizzled]
    __shared__ __bf16 Vlds[2][64 * 64];   // [d][key-blocks swizzled]
    __shared__ __bf16 Plds[4][16][68];    // per-wave P[q][key], 136B stride (2-way max)

    const int tid = threadIdx.x;
    const int lane = tid & 63;
    const int w = tid >> 6;               // 0..3
    const int l15 = lane & 15, lhi = lane >> 4;
    const int l7 = l15 & 7;

    // id&7 = XCD; within XCD: qt descending (LPT), interleaved over 4 bh streams
    const int id = blockIdx.x;            // 0..1023
    const int x = id & 7, j = id >> 3;    // j 0..127
    const int qt = 31 - (j >> 2);         // 31..0
    const int bh = 4 * x + (j & 3);       // 4 streams per XCD (2MB L2 working set)
    const int b = bh >> 4, h = bh & 15;

    const int srow = (lane >> 3);
    const int scs = (lane & 7) ^ srow;
    const __bf16* Kbase = K + (size_t)b * SLEN * DIM + h * HD;
    const __bf16* Vbase = Vt + (size_t)bh * 64 * SLEN;

    auto stage = [&](int buf, int kt) {
#pragma unroll
        for (int i = 0; i < 2; ++i) {
            int r0 = i * 32 + 8 * w + srow;
            const __bf16* sk = Kbase + (size_t)(kt * 64 + r0) * DIM + scs * 8;
            const __bf16* sv = Vbase + (size_t)r0 * SLEN + kt * 64 + scs * 8;
            __builtin_amdgcn_global_load_lds((const __attribute__((address_space(1))) void*)sk,
                                             (__attribute__((address_space(3))) void*)&Klds[buf][r0 * 64],
                                             16, 0, 0);
            __builtin_amdgcn_global_load_lds((const __attribute__((address_space(1))) void*)sv,
                                             (__attribute__((address_space(3))) void*)&Vlds[buf][r0 * 64],
                                             16, 0, 0);
        }
    };

    const int q0 = qt * 64;
    const int qrow_g = q0 + w * 16 + l15;
    const size_t qbase = (size_t)(b * SLEN + qrow_g) * DIM + h * HD;
    const bf16x8 qf0 = *(const bf16x8*)&Q[qbase + lhi * 8];
    const bf16x8 qf1 = *(const bf16x8*)&Q[qbase + 32 + lhi * 8];

    float m = -1e30f, lsum = 0.f;
    f32x4 acc[4] = {};  // acc[nd][r]: d = nd*16 + lhi*4 + r, q = l15

    const int nkt = qt + 1;  // kv tiles 0..qt
    stage(0, 0);
    for (int kt = 0; kt < nkt; ++kt) {
        const int cur = kt & 1;
        __syncthreads();  // drains vmcnt: buf[cur] staged; buf[cur^1] free
        if (kt + 1 < nkt) stage(cur ^ 1, kt + 1);

        // ---- S^T = K Q^T : lane owns q=l15; keys nb*16 + lhi*4 + r ----
        f32x4 sT[4];
        __builtin_amdgcn_s_setprio(1);
#pragma unroll
        for (int nb = 0; nb < 4; ++nb) {
            const int krow = (nb * 16 + l15) * 64;
            bf16x8 k0 = *(const bf16x8*)&Klds[cur][krow + 8 * ((0 + lhi) ^ l7)];
            bf16x8 k1 = *(const bf16x8*)&Klds[cur][krow + 8 * ((4 + lhi) ^ l7)];
            f32x4 a = {};
            a = MFMA(k0, qf0, a);
            a = MFMA(k1, qf1, a);
            sT[nb] = a;
        }
        __builtin_amdgcn_s_setprio(0);
        if (kt == qt) {  // only the diagonal tile is partially masked
#pragma unroll
            for (int nb = 0; nb < 4; ++nb)
#pragma unroll
                for (int r = 0; r < 4; ++r)
                    if (nb * 16 + lhi * 4 + r > w * 16 + l15) sT[nb][r] = -1e30f;
        }
        // ---- online softmax (lane-local + 2 shfl over lhi groups) ----
        float mx = -1e30f;
#pragma unroll
        for (int nb = 0; nb < 4; ++nb)
#pragma unroll
            for (int r = 0; r < 4; ++r) mx = fmaxf(mx, sT[nb][r]);
        mx = fmaxf(mx, __shfl_xor(mx, 16));
        mx = fmaxf(mx, __shfl_xor(mx, 32));
        // defer-max (T13): skip rescale while max growth <= 8 (exp2 units)
        if (!__all(mx <= m + 8.0f)) {
            const float mnew = fmaxf(m, mx);
            const float corr = exp2f(m - mnew);
            m = mnew;
            lsum *= corr;
#pragma unroll
            for (int nd = 0; nd < 4; ++nd)
#pragma unroll
                for (int r = 0; r < 4; ++r) acc[nd][r] *= corr;
        }
        float rs = 0.f;
#pragma unroll
        for (int nb = 0; nb < 4; ++nb) {
            bf16x4 pk;
#pragma unroll
            for (int r = 0; r < 4; ++r) {
                float pv = exp2f(sT[nb][r] - m);
                rs += pv;
                pk[r] = (__bf16)pv;
            }
            *(bf16x4*)&Plds[w][l15][nb * 16 + lhi * 4] = pk;
        }
        rs += __shfl_xor(rs, 16);
        rs += __shfl_xor(rs, 32);
        lsum += rs;

        // ---- O^T += V^T P^T : A = V^T frag, B = P^T frag ----
        __builtin_amdgcn_s_setprio(1);
#pragma unroll
        for (int kk = 0; kk < 2; ++kk) {
            const bf16x8 pf = *(const bf16x8*)&Plds[w][l15][kk * 32 + lhi * 8];
#pragma unroll
            for (int nd = 0; nd < 4; ++nd) {
                const int vrow = (nd * 16 + l15) * 64;
                bf16x8 vf = *(const bf16x8*)&Vlds[cur][vrow + 8 * ((kk * 4 + lhi) ^ l7)];
                acc[nd] = MFMA(vf, pf, acc[nd]);
            }
        }
        __builtin_amdgcn_s_setprio(0);
    }
    // ---- epilogue: lane-local 1/lsum, packed bf16x4 stores ----
    const float inv = 1.0f / lsum;
#pragma unroll
    for (int nd = 0; nd < 4; ++nd) {
        bf16x4 o;
#pragma unroll
        for (int r = 0; r < 4; ++r) o[r] = (__bf16)(acc[nd][r] * inv);
        *(bf16x4*)&Y[(size_t)(b * SLEN + qrow_g) * DIM + h * HD + nd * 16 + lhi * 4] = o;
    }
}

// ---------------- launcher ----------------
extern "C" void kernel_launch(void* const* d_in, const int* in_sizes, int n_in,
                              void* d_out, int out_size, void* d_ws, size_t ws_size,
                              hipStream_t stream) {
    const float* x = (const float*)d_in[0];
    const float* Wq = (const float*)d_in[1];
    const float* Wk = (const float*)d_in[2];
    const float* Wv = (const float*)d_in[3];
    const float* Wo = (const float*)d_in[4];
    float* out = (float*)d_out;

    const size_t XN = (size_t)4096 * 1024;
    const size_t WN = (size_t)1024 * 1024;

    __bf16* xb = (__bf16*)d_ws;
    __bf16* qb = xb + XN;
    __bf16* kb = qb + XN;
    __bf16* vtb = kb + XN;   // transposed V: [(b*16+h)*64 + d][SLEN]
    __bf16* wqb = vtb + XN;
    __bf16* wkb = wqb + WN;
    __bf16* wvb = wkb + WN;
    __bf16* wob = wvb + WN;
    __bf16* yb = xb;  // alias: attn writes y after x's last read (QKV GEMM)

    cvt_bf16<<<XN / 8 / 256, 256, 0, stream>>>(x, xb, (int)XN);
    dim3 gw(WN / 8 / 256, 4);
    cvt_w4<<<gw, 256, 0, stream>>>(Wq, Wk, Wv, Wo, wqb, wkb, wvb, wob);

    dim3 gq(24, 32);  // 3072/128 x 4096/128
    gemm_qkv<<<gq, 256, 0, stream>>>(xb, wqb, wkb, wvb, qb, kb, vtb);

    int pairs = 4096 * (DIM / 2);
    dim3 gr(pairs / 256, 2);
    rope2<<<gr, 256, 0, stream>>>(qb, kb);

    attn_kernel<<<1024, 256, 0, stream>>>(qb, kb, vtb, yb);

    dim3 go(8, 64);  // 1024/128 x 4096/64
    gemm_o<<<go, 256, 0, stream>>>(yb, wob, out);
}